// Round 14
// baseline (88.024 us; speedup 1.0000x reference)
//
#include <hip/hip_runtime.h>
#include <stdint.h>

#define LOG2PI_F 1.8378770664093453f
#define D_DIM 1024

typedef float v4f __attribute__((ext_vector_type(4)));

// ---------- deterministic counter-based RNG (splitmix64 finalizer) ----------
__device__ __forceinline__ uint32_t mix64_32(uint64_t z) {
    z ^= z >> 33; z *= 0xff51afd7ed558ccdULL;
    z ^= z >> 33; z *= 0xc4ceb9fe1a85ec53ULL;
    z ^= z >> 33;
    return (uint32_t)z;
}
// strictly inside (0,1): [2^-24, 1-2^-24]
__device__ __forceinline__ float unif01(uint32_t stream, uint32_t idx) {
    uint32_t h = mix64_32(((uint64_t)stream << 32) | (uint64_t)idx);
    return (float)(h >> 9) * 0x1p-23f + 0x1p-24f;
}
__device__ __forceinline__ float softplusf(float r) { return log1pf(expf(r)); }

union F4 { v4f v; float f[4]; };

// =====================================================================
// Fused main kernel: 1280 blocks x 256 thr, 16KB LDS union for BOTH paths.
//  bid%5==4 -> cls block (256 total, interleaved => co-resident with lik;
//              retires in ~4us, pending lik blocks backfill => tail absorbed)
//  else     -> lik block (1024 total, 64 rows, byte-equiv to R11's A)
// cls stages only HF/AF (classifier coeffs) in the union; cluster mu/rho
// are read per-row from L2 (8KB, shared by all cls blocks) + softplus on
// the fly (pattern validated in R4).
// =====================================================================
__global__ __launch_bounds__(256) void hdp_main_kernel(
    const float* __restrict__ x, const float* __restrict__ mu_c,
    const float* __restrict__ rho_c, const float* __restrict__ mu_f,
    const float* __restrict__ rho_f, float* __restrict__ out,
    double* __restrict__ partial)
{
    __shared__ float C0[D_DIM], C1[D_DIM], C2[D_DIM], C3[D_DIM];  // 16KB union
    __shared__ float wred[4][4];
    __shared__ double wpart[4];
    const int bid = blockIdx.x;
    const int q = bid / 5, rr = bid % 5;
    const bool is_cls = (rr == 4);
    const int tid = threadIdx.x, wid = tid >> 6, lane = tid & 63;

    // ---- setup: stage this path's coefficients H=0.5/s^2, A=mu/s^2 ----
    const float* mu_s  = is_cls ? mu_f  : mu_c;
    const float* rho_s = is_cls ? rho_f : rho_c;
    float sls0 = 0.f, sls1 = 0.f, bq0 = 0.f, bq1 = 0.f;
    {
        const int d = tid * 4;
        F4 r0, r1, m0, m1;
        r0.v = *(const v4f*)(rho_s + d);
        r1.v = *(const v4f*)(rho_s + D_DIM + d);
        m0.v = *(const v4f*)(mu_s + d);
        m1.v = *(const v4f*)(mu_s + D_DIM + d);
#pragma unroll
        for (int e = 0; e < 4; ++e) {
            float s0 = softplusf(r0.f[e]);
            float i0 = 1.f / (s0 * s0);
            C0[d + e] = 0.5f * i0; C1[d + e] = m0.f[e] * i0;
            sls0 += logf(s0); bq0 += 0.5f * m0.f[e] * m0.f[e] * i0;
            float s1 = softplusf(r1.f[e]);
            float i1 = 1.f / (s1 * s1);
            C2[d + e] = 0.5f * i1; C3[d + e] = m1.f[e] * i1;
            sls1 += logf(s1); bq1 += 0.5f * m1.f[e] * m1.f[e] * i1;
        }
    }
#pragma unroll
    for (int off = 32; off; off >>= 1) {
        sls0 += __shfl_xor(sls0, off); sls1 += __shfl_xor(sls1, off);
        bq0  += __shfl_xor(bq0,  off); bq1  += __shfl_xor(bq1,  off);
    }
    if (lane == 0) {
        wred[wid][0] = sls0; wred[wid][1] = sls1;
        wred[wid][2] = bq0;  wred[wid][3] = bq1;
    }
    __syncthreads();
    const float SLS0 = wred[0][0] + wred[1][0] + wred[2][0] + wred[3][0];
    const float SLS1 = wred[0][1] + wred[1][1] + wred[2][1] + wred[3][1];
    const float BQ0  = wred[0][2] + wred[1][2] + wred[2][2] + wred[3][2];
    const float BQ1  = wred[0][3] + wred[1][3] + wred[2][3] + wred[3][3];
    const float CF0 = -0.5f * 1024.f * LOG2PI_F - SLS0 - BQ0;   // const_t - bq_t
    const float CF1 = -0.5f * 1024.f * LOG2PI_F - SLS1 - BQ1;

    if (!is_cls) {
        // ======================= lik path (R11 body) =======================
        const float ent = 0.5f * 1024.f * (LOG2PI_F + 1.f) + 0.5f * (SLS0 + SLS1);
        const float V0 = CF0 + ent, V1 = CF1 + ent;
        const int lik_blk = q * 4 + rr;             // 0..1023 bijective
        const int rowbase = lik_blk * 64 + wid * 16;
        double wsum = 0.0;
        for (int g = 0; g < 4; ++g) {               // 4 groups of 4 rows per wave
            const int r0 = rowbase + g * 4;
            float q0[4] = {0.f, 0.f, 0.f, 0.f}, q1[4] = {0.f, 0.f, 0.f, 0.f};
#pragma unroll
            for (int k = 0; k < 4; ++k) {
                const int d = k * 256 + lane * 4;   // coalesced 16B/lane
                F4 xv[4];
#pragma unroll
                for (int r = 0; r < 4; ++r)
                    xv[r].v = *(const v4f*)(x + (size_t)(r0 + r) * D_DIM + d);
                F4 h0, a0v, h1, a1v;
                h0.v  = *(const v4f*)&C0[d];
                a0v.v = *(const v4f*)&C1[d];
                h1.v  = *(const v4f*)&C2[d];
                a1v.v = *(const v4f*)&C3[d];
#pragma unroll
                for (int r = 0; r < 4; ++r) {
#pragma unroll
                    for (int e = 0; e < 4; ++e) {
                        float xe = xv[r].f[e];
                        float xx = xe * xe;
                        q0[r] = fmaf(xx, h0.f[e], q0[r]);  q0[r] = fmaf(-xe, a0v.f[e], q0[r]);
                        q1[r] = fmaf(xx, h1.f[e], q1[r]);  q1[r] = fmaf(-xe, a1v.f[e], q1[r]);
                    }
                }
            }
#pragma unroll
            for (int r = 0; r < 4; ++r) {
                float a = q0[r], b = q1[r];
#pragma unroll
                for (int off = 32; off; off >>= 1) { a += __shfl_xor(a, off); b += __shfl_xor(b, off); }
                const uint32_t row = (uint32_t)(r0 + r);
                float u0 = unif01(1u, 2u * row), u1v = unif01(1u, 2u * row + 1u);
                float lp0 = logf(u0);
                float lp1 = logf(u1v) + logf(1.f - u0);
                float v0 = V0 - a, v1 = V1 - b;
                float s0 = lp0 + v0, s1 = lp1 + v1;
                float mx = fmaxf(s0, s1);
                float e0 = expf(s0 - mx), e1 = expf(s1 - mx);
                float phi0 = e0 / (e0 + e1);
                wsum += (double)(phi0 * v0 + (1.f - phi0) * v1);
            }
        }
        if (lane == 0) wpart[wid] = wsum;
        __syncthreads();
        if (tid == 0) partial[lik_blk] = wpart[0] + wpart[1] + wpart[2] + wpart[3];
    } else {
        // ======================= cls path (16KB, R4-validated body) =======
        for (int r = 0; r < 4; ++r) {
            const uint32_t j = (uint32_t)q * 16u + (uint32_t)wid * 4u + (uint32_t)r;
            // mixture weights + categorical draw (wave-uniform)
            float b0 = unif01(2u, 2u * j), b1 = unif01(2u, 2u * j + 1u);
            float wn0 = b0 / (b0 + b1 * (1.f - b0));
            int dr = (unif01(3u, j) < wn0) ? 0 : 1;
            float bi0 = unif01(5u, 2u * j), bi1 = unif01(5u, 2u * j + 1u);
            float pi0 = bi0, pi1 = bi1 * (1.f - bi0);
            const float* MUg = mu_c + (size_t)dr * D_DIM;
            const float* RHg = rho_c + (size_t)dr * D_DIM;
            float qf0 = 0.f, qf1 = 0.f;
#pragma unroll
            for (int k = 0; k < 4; ++k) {
                const int dd = k * 256 + lane * 4;
                F4 mu, rh, h0, a0, h1, a1;
                mu.v = *(const v4f*)(MUg + dd);     // L2-resident (8KB shared)
                rh.v = *(const v4f*)(RHg + dd);
                h0.v = *(const v4f*)&C0[dd];
                a0.v = *(const v4f*)&C1[dd];
                h1.v = *(const v4f*)&C2[dd];
                a1.v = *(const v4f*)&C3[dd];
#pragma unroll
                for (int e = 0; e < 4; e += 2) {
                    // Box-Muller pair for dims (dd+e, dd+e+1)
                    uint32_t p = j * 512u + (uint32_t)((dd + e) >> 1);
                    float uu1 = unif01(4u, p), uu2 = unif01(6u, p);
                    float rad = sqrtf(-2.f * logf(uu1));
                    float sn, cs;
                    __sincosf(6.283185307179586f * uu2, &sn, &cs);
                    float sd0 = softplusf(rh.f[e]), sd1 = softplusf(rh.f[e + 1]);
                    float mc0 = fmaf(sd0, rad * cs, mu.f[e]);
                    float mc1 = fmaf(sd1, rad * sn, mu.f[e + 1]);
                    float xx0 = mc0 * mc0, xx1 = mc1 * mc1;
                    qf0 = fmaf(xx0, h0.f[e], qf0);      qf0 = fmaf(-mc0, a0.f[e], qf0);
                    qf0 = fmaf(xx1, h0.f[e + 1], qf0);  qf0 = fmaf(-mc1, a0.f[e + 1], qf0);
                    qf1 = fmaf(xx0, h1.f[e], qf1);      qf1 = fmaf(-mc0, a1.f[e], qf1);
                    qf1 = fmaf(xx1, h1.f[e + 1], qf1);  qf1 = fmaf(-mc1, a1.f[e + 1], qf1);
                }
            }
#pragma unroll
            for (int off = 32; off; off >>= 1) { qf0 += __shfl_xor(qf0, off); qf1 += __shfl_xor(qf1, off); }
            float lp0 = CF0 - qf0, lp1 = CF1 - qf1;
            float mx = fmaxf(lp0, lp1);
            float e0 = expf(lp0 - mx), e1 = expf(lp1 - mx);
            float inv = 1.f / (e0 + e1);
            if (lane == 0) {
                out[2u * j]      = pi0 * e0 * inv;
                out[2u * j + 1u] = pi1 * e1 * inv;
            }
        }
    }
}

// =====================================================================
// Final deterministic reduce: 1024 f64 partials -> out[8192]
// =====================================================================
__global__ void hdp_final_kernel(const double* __restrict__ partial,
                                 float* __restrict__ out)
{
    const int lane = threadIdx.x;  // 64 threads
    double s = 0.0;
    for (int i = lane; i < 1024; i += 64) s += partial[i];
#pragma unroll
    for (int off = 32; off; off >>= 1) s += __shfl_xor(s, off);
    if (lane == 0) out[8192] = (float)(-s / 65536.0);
}

extern "C" void kernel_launch(void* const* d_in, const int* in_sizes, int n_in,
                              void* d_out, int out_size, void* d_ws, size_t ws_size,
                              hipStream_t stream) {
    const float* x     = (const float*)d_in[0];
    const float* mu_c  = (const float*)d_in[1];
    const float* rho_c = (const float*)d_in[2];
    const float* mu_f  = (const float*)d_in[3];
    const float* rho_f = (const float*)d_in[4];
    float* out = (float*)d_out;        // 8192 logits + 1 scalar, f32
    double* partial = (double*)d_ws;   // 1024 doubles = 8 KB scratch

    hipLaunchKernelGGL(hdp_main_kernel, dim3(1280), dim3(256), 0, stream,
                       x, mu_c, rho_c, mu_f, rho_f, out, partial);
    hipLaunchKernelGGL(hdp_final_kernel, dim3(1), dim3(64), 0, stream,
                       partial, out);
}

// Round 15
// 64.188 us; speedup vs baseline: 1.3714x; 1.3714x over previous
//
#include <hip/hip_runtime.h>
#include <stdint.h>

#define LOG2PI_F 1.8378770664093453f
#define D_DIM 1024

typedef float v4f __attribute__((ext_vector_type(4)));

// ---------- deterministic counter-based RNG (splitmix64 finalizer) ----------
__device__ __forceinline__ uint32_t mix64_32(uint64_t z) {
    z ^= z >> 33; z *= 0xff51afd7ed558ccdULL;
    z ^= z >> 33; z *= 0xc4ceb9fe1a85ec53ULL;
    z ^= z >> 33;
    return (uint32_t)z;
}
// strictly inside (0,1): [2^-24, 1-2^-24]
__device__ __forceinline__ float unif01(uint32_t stream, uint32_t idx) {
    uint32_t h = mix64_32(((uint64_t)stream << 32) | (uint64_t)idx);
    return (float)(h >> 9) * 0x1p-23f + 0x1p-24f;
}
__device__ __forceinline__ float softplusf(float r) { return log1pf(expf(r)); }

union F4 { v4f v; float f[4]; };

// =====================================================================
// Kernel A: neg_likelihood partial sums.  1024 blocks x 256 thr,
// 64 rows/block (4 waves x 16 rows), coefficients in LDS.
// BYTE-IDENTICAL to the proven 64.29us R11 version.
// =====================================================================
__global__ __launch_bounds__(256) void hdp_lik_kernel(
    const float* __restrict__ x, const float* __restrict__ mu_c,
    const float* __restrict__ rho_c, double* __restrict__ partial)
{
    __shared__ float H0[D_DIM], A0[D_DIM], H1[D_DIM], A1[D_DIM];
    __shared__ float wred[4][4];
    __shared__ double wpart[4];
    const int tid = threadIdx.x, wid = tid >> 6, lane = tid & 63;

    // ---- per-component coefficients: H = 0.5/sigma^2, A = mu/sigma^2 ----
    float sls0 = 0.f, sls1 = 0.f, bq0 = 0.f, bq1 = 0.f;
    {
        const int d = tid * 4;
        F4 r0, r1, m0, m1;
        r0.v = *(const v4f*)(rho_c + d);
        r1.v = *(const v4f*)(rho_c + D_DIM + d);
        m0.v = *(const v4f*)(mu_c + d);
        m1.v = *(const v4f*)(mu_c + D_DIM + d);
#pragma unroll
        for (int e = 0; e < 4; ++e) {
            float s0 = softplusf(r0.f[e]);
            float i0 = 1.f / (s0 * s0);
            H0[d + e] = 0.5f * i0; A0[d + e] = m0.f[e] * i0;
            sls0 += logf(s0); bq0 += 0.5f * m0.f[e] * m0.f[e] * i0;
            float s1 = softplusf(r1.f[e]);
            float i1 = 1.f / (s1 * s1);
            H1[d + e] = 0.5f * i1; A1[d + e] = m1.f[e] * i1;
            sls1 += logf(s1); bq1 += 0.5f * m1.f[e] * m1.f[e] * i1;
        }
    }
    // wave butterfly + one cross-wave LDS round (barrier fences H/A too)
#pragma unroll
    for (int off = 32; off; off >>= 1) {
        sls0 += __shfl_xor(sls0, off); sls1 += __shfl_xor(sls1, off);
        bq0  += __shfl_xor(bq0,  off); bq1  += __shfl_xor(bq1,  off);
    }
    if (lane == 0) {
        wred[wid][0] = sls0; wred[wid][1] = sls1;
        wred[wid][2] = bq0;  wred[wid][3] = bq1;
    }
    __syncthreads();
    const float SLS0 = wred[0][0] + wred[1][0] + wred[2][0] + wred[3][0];
    const float SLS1 = wred[0][1] + wred[1][1] + wred[2][1] + wred[3][1];
    const float BQ0  = wred[0][2] + wred[1][2] + wred[2][2] + wred[3][2];
    const float BQ1  = wred[0][3] + wred[1][3] + wred[2][3] + wred[3][3];
    const float ent = 0.5f * 1024.f * (LOG2PI_F + 1.f) + 0.5f * (SLS0 + SLS1);
    const float V0 = ent - 0.5f * 1024.f * LOG2PI_F - SLS0 - BQ0;
    const float V1 = ent - 0.5f * 1024.f * LOG2PI_F - SLS1 - BQ1;

    double wsum = 0.0;
    const int rowbase = blockIdx.x * 64 + wid * 16;
    for (int g = 0; g < 4; ++g) {          // 4 groups of 4 rows per wave
        const int r0 = rowbase + g * 4;
        float q0[4] = {0.f, 0.f, 0.f, 0.f}, q1[4] = {0.f, 0.f, 0.f, 0.f};
#pragma unroll
        for (int k = 0; k < 4; ++k) {
            const int d = k * 256 + lane * 4;   // coalesced: lane i -> consecutive 16B
            // issue all 4 row-loads FIRST (keep 4 outstanding)
            F4 xv[4];
#pragma unroll
            for (int r = 0; r < 4; ++r)
                xv[r].v = *(const v4f*)(x + (size_t)(r0 + r) * D_DIM + d);
            F4 h0, a0v, h1, a1v;
            h0.v  = *(const v4f*)&H0[d];
            a0v.v = *(const v4f*)&A0[d];
            h1.v  = *(const v4f*)&H1[d];
            a1v.v = *(const v4f*)&A1[d];
#pragma unroll
            for (int r = 0; r < 4; ++r) {
#pragma unroll
                for (int e = 0; e < 4; ++e) {
                    float xe = xv[r].f[e];
                    float xx = xe * xe;
                    q0[r] = fmaf(xx, h0.f[e], q0[r]);  q0[r] = fmaf(-xe, a0v.f[e], q0[r]);
                    q1[r] = fmaf(xx, h1.f[e], q1[r]);  q1[r] = fmaf(-xe, a1v.f[e], q1[r]);
                }
            }
        }
#pragma unroll
        for (int r = 0; r < 4; ++r) {
            float a = q0[r], b = q1[r];
#pragma unroll
            for (int off = 32; off; off >>= 1) { a += __shfl_xor(a, off); b += __shfl_xor(b, off); }
            const uint32_t row = (uint32_t)(r0 + r);
            // Beta(1,1) = U(0,1) stick-breaking weights (distributionally faithful)
            float u0 = unif01(1u, 2u * row), u1v = unif01(1u, 2u * row + 1u);
            float lp0 = logf(u0);
            float lp1 = logf(u1v) + logf(1.f - u0);
            float v0 = V0 - a, v1 = V1 - b;
            float s0 = lp0 + v0, s1 = lp1 + v1;
            float mx = fmaxf(s0, s1);
            float e0 = expf(s0 - mx), e1 = expf(s1 - mx);
            float phi0 = e0 / (e0 + e1);
            wsum += (double)(phi0 * v0 + (1.f - phi0) * v1);
        }
    }
    if (lane == 0) wpart[wid] = wsum;
    __syncthreads();
    if (tid == 0) partial[blockIdx.x] = wpart[0] + wpart[1] + wpart[2] + wpart[3];
}

// =====================================================================
// Kernel B: MC sample + classifier logits + (block 256) final reduce.
// BYTE-IDENTICAL to the proven R7/R11 version.
// =====================================================================
__global__ __launch_bounds__(256) void hdp_cls_kernel(
    const float* __restrict__ mu_c, const float* __restrict__ rho_c,
    const float* __restrict__ mu_f, const float* __restrict__ rho_f,
    const double* __restrict__ partial, float* __restrict__ out)
{
    const int tid = threadIdx.x, wid = tid >> 6, lane = tid & 63;

    if (blockIdx.x == 256) {
        // ---- final deterministic reduce ----
        if (wid == 0) {
            double s = 0.0;
            for (int i = lane; i < 1024; i += 64) s += partial[i];
#pragma unroll
            for (int off = 32; off; off >>= 1) s += __shfl_xor(s, off);
            if (lane == 0) out[8192] = (float)(-s / 65536.0);
        }
        return;
    }

    __shared__ float MU0[D_DIM], SD0[D_DIM], MU1[D_DIM], SD1[D_DIM];
    __shared__ float HF0[D_DIM], AF0[D_DIM], HF1[D_DIM], AF1[D_DIM];
    __shared__ float wred[4][2];

    float cf0 = 0.f, cf1 = 0.f;   // accumulates -(log sf + 0.5 mf^2/sf^2)
    {
        const int d = tid * 4;
#pragma unroll
        for (int e = 0; e < 4; ++e) {
            MU0[d + e] = mu_c[d + e];           SD0[d + e] = softplusf(rho_c[d + e]);
            MU1[d + e] = mu_c[D_DIM + d + e];   SD1[d + e] = softplusf(rho_c[D_DIM + d + e]);
            float mf0 = mu_f[d + e], sf0 = softplusf(rho_f[d + e]);
            float i0 = 1.f / (sf0 * sf0);
            HF0[d + e] = 0.5f * i0; AF0[d + e] = mf0 * i0;
            cf0 -= logf(sf0) + 0.5f * mf0 * mf0 * i0;
            float mf1 = mu_f[D_DIM + d + e], sf1 = softplusf(rho_f[D_DIM + d + e]);
            float i1 = 1.f / (sf1 * sf1);
            HF1[d + e] = 0.5f * i1; AF1[d + e] = mf1 * i1;
            cf1 -= logf(sf1) + 0.5f * mf1 * mf1 * i1;
        }
    }
#pragma unroll
    for (int off = 32; off; off >>= 1) {
        cf0 += __shfl_xor(cf0, off); cf1 += __shfl_xor(cf1, off);
    }
    if (lane == 0) { wred[wid][0] = cf0; wred[wid][1] = cf1; }
    __syncthreads();
    const float CF0 = -0.5f * 1024.f * LOG2PI_F
                    + wred[0][0] + wred[1][0] + wred[2][0] + wred[3][0];
    const float CF1 = -0.5f * 1024.f * LOG2PI_F
                    + wred[0][1] + wred[1][1] + wred[2][1] + wred[3][1];

    for (int r = 0; r < 4; ++r) {
        const uint32_t j = (uint32_t)blockIdx.x * 16u + (uint32_t)wid * 4u + (uint32_t)r;
        // mixture weights + categorical draw (wave-uniform, no divergence)
        float b0 = unif01(2u, 2u * j), b1 = unif01(2u, 2u * j + 1u);
        float wn0 = b0 / (b0 + b1 * (1.f - b0));
        int dr = (unif01(3u, j) < wn0) ? 0 : 1;
        float bi0 = unif01(5u, 2u * j), bi1 = unif01(5u, 2u * j + 1u);
        float pi0 = bi0, pi1 = bi1 * (1.f - bi0);
        const float* MU = dr ? &MU1[0] : &MU0[0];
        const float* SD = dr ? &SD1[0] : &SD0[0];
        float qf0 = 0.f, qf1 = 0.f;
#pragma unroll
        for (int k = 0; k < 4; ++k) {
            const int dd = k * 256 + lane * 4;
            F4 mu, sd, h0, a0, h1, a1;
            mu.v = *(const v4f*)&MU[dd];
            sd.v = *(const v4f*)&SD[dd];
            h0.v = *(const v4f*)&HF0[dd];
            a0.v = *(const v4f*)&AF0[dd];
            h1.v = *(const v4f*)&HF1[dd];
            a1.v = *(const v4f*)&AF1[dd];
#pragma unroll
            for (int e = 0; e < 4; e += 2) {
                // Box-Muller pair for dims (dd+e, dd+e+1)
                uint32_t p = j * 512u + (uint32_t)((dd + e) >> 1);
                float uu1 = unif01(4u, p), uu2 = unif01(6u, p);
                float rad = sqrtf(-2.f * logf(uu1));
                float sn, cs;
                __sincosf(6.283185307179586f * uu2, &sn, &cs);
                float mc0 = fmaf(sd.f[e],     rad * cs, mu.f[e]);
                float mc1 = fmaf(sd.f[e + 1], rad * sn, mu.f[e + 1]);
                float xx0 = mc0 * mc0, xx1 = mc1 * mc1;
                qf0 = fmaf(xx0, h0.f[e], qf0);      qf0 = fmaf(-mc0, a0.f[e], qf0);
                qf0 = fmaf(xx1, h0.f[e + 1], qf0);  qf0 = fmaf(-mc1, a0.f[e + 1], qf0);
                qf1 = fmaf(xx0, h1.f[e], qf1);      qf1 = fmaf(-mc0, a1.f[e], qf1);
                qf1 = fmaf(xx1, h1.f[e + 1], qf1);  qf1 = fmaf(-mc1, a1.f[e + 1], qf1);
            }
        }
#pragma unroll
        for (int off = 32; off; off >>= 1) { qf0 += __shfl_xor(qf0, off); qf1 += __shfl_xor(qf1, off); }
        float lp0 = CF0 - qf0, lp1 = CF1 - qf1;
        float mx = fmaxf(lp0, lp1);
        float e0 = expf(lp0 - mx), e1 = expf(lp1 - mx);
        float inv = 1.f / (e0 + e1);
        if (lane == 0) {
            out[2u * j]      = pi0 * e0 * inv;
            out[2u * j + 1u] = pi1 * e1 * inv;
        }
    }
}

extern "C" void kernel_launch(void* const* d_in, const int* in_sizes, int n_in,
                              void* d_out, int out_size, void* d_ws, size_t ws_size,
                              hipStream_t stream) {
    const float* x     = (const float*)d_in[0];
    const float* mu_c  = (const float*)d_in[1];
    const float* rho_c = (const float*)d_in[2];
    const float* mu_f  = (const float*)d_in[3];
    const float* rho_f = (const float*)d_in[4];
    float* out = (float*)d_out;        // 8192 logits + 1 scalar, f32
    double* partial = (double*)d_ws;   // 1024 doubles = 8 KB scratch

    hipLaunchKernelGGL(hdp_lik_kernel, dim3(1024), dim3(256), 0, stream,
                       x, mu_c, rho_c, partial);
    hipLaunchKernelGGL(hdp_cls_kernel, dim3(257), dim3(256), 0, stream,
                       mu_c, rho_c, mu_f, rho_f, partial, out);
}